// Round 4
// baseline (761.314 us; speedup 1.0000x reference)
//
#include <hip/hip_runtime.h>

// MLPP: 8x 256x256 GEMMs over gathered views of x[4,32,32,32,256] (fp32 in/out).
// pack -> k_ip (fused att+c+h+w+combine+W1+residual -> x1_blk) -> k_d -> k_fin
// k_ip: per tile t, 160KiB LDS = XS(128K) + BB(32K bounce). sum accs held in regs;
// h/w/att merged via 64-col n-chunk GEMMs bounced through BB in (pos,c) layout.

typedef __attribute__((ext_vector_type(8))) short bf16x8;
typedef __attribute__((ext_vector_type(8))) unsigned short u16x8;
typedef __attribute__((ext_vector_type(4))) float f32x4;
typedef __attribute__((ext_vector_type(4))) unsigned short u16x4;
typedef unsigned short u16;
typedef unsigned int u32;

#define DEV __device__ __forceinline__

DEV u16 f2b(float f) {  // fp32 -> bf16 RNE
  union { float f; u32 u; } v; v.f = f;
  u32 r = v.u + 0x7FFFu + ((v.u >> 16) & 1u);
  return (u16)(r >> 16);
}
DEV float b2f(u16 b) {
  union { u32 u; float f; } v; v.u = ((u32)b) << 16; return v.f;
}

// 512B-pitch LDS tiles, XOR swizzle over 16B slots (32 slots/row).
DEV int lds_off(int row, int colByte) {
  return (row << 9) + (colByte ^ ((row & 31) << 4));
}
DEV bf16x8 ld_lds(const u16* lds, int row, int colByte) {
  return *(const bf16x8*)((const char*)lds + lds_off(row, colByte));
}
DEV bf16x8 ld_glb(const u16* g, int row, int kByte) {  // row-major [.][256] bf16
  return *(const bf16x8*)((const char*)g + (row << 9) + kByte);
}

template <int MI, int NJ>
DEV void zero_acc(f32x4 acc[MI][NJ]) {
#pragma unroll
  for (int i = 0; i < MI; ++i)
#pragma unroll
    for (int j = 0; j < NJ; ++j) {
      acc[i][j][0] = 0.f; acc[i][j][1] = 0.f; acc[i][j][2] = 0.f; acc[i][j][3] = 0.f;
    }
}

// D[m][n] = sum_k P[m][k] * Q[n][k], K=256. MI/NJ = 16x16 tiles per wave.
template <int MI, int NJ, typename LA, typename LB>
DEV void gemmT(LA loadA, LB loadB, f32x4 acc[MI][NJ]) {
#pragma unroll
  for (int kk = 0; kk < 8; ++kk) {
    bf16x8 a[MI], b[NJ];
#pragma unroll
    for (int i = 0; i < MI; ++i) a[i] = loadA(i, kk);
#pragma unroll
    for (int j = 0; j < NJ; ++j) b[j] = loadB(j, kk);
#pragma unroll
    for (int i = 0; i < MI; ++i)
#pragma unroll
      for (int j = 0; j < NJ; ++j)
        acc[i][j] = __builtin_amdgcn_mfma_f32_16x16x32_bf16(a[i], b[j], acc[i][j], 0, 0, 0);
  }
}

#define WAVE_SETUP                  \
  const int tid = threadIdx.x;      \
  const int lane = tid & 63;        \
  const int wave = tid >> 6;        \
  const int wm = wave >> 2;         \
  const int wn = wave & 3;          \
  const int lr = lane & 15;         \
  const int lk = lane >> 4;

// ---------- weight pack: WT[s][n*256+k] = W_s[k*256+n] (+I for s==7) ----------
__global__ void k_pack_all(const float* W0, const float* W1p, const float* W2p,
                           const float* W3p, const float* W4p, const float* W5p,
                           const float* W6p, const float* W7p, u16* __restrict__ WT) {
  int bi = blockIdx.x;
  int wsel = bi >> 8, n = bi & 255;
  const float* W;
  switch (wsel) {
    case 0: W = W0; break; case 1: W = W1p; break; case 2: W = W2p; break;
    case 3: W = W3p; break; case 4: W = W4p; break; case 5: W = W5p; break;
    case 6: W = W6p; break; default: W = W7p; break;
  }
  u16* dst = WT + wsel * 65536;
  int k0 = threadIdx.x * 4;
#pragma unroll
  for (int i = 0; i < 4; ++i) {
    int k = k0 + i;
    float v = W[k * 256 + n];
    if (wsel == 7 && k == n) v += 1.0f;
    dst[n * 256 + k] = f2b(v);
  }
}

// ---------- fused ip_mlp: x1 = x + ((1+att)*(xc+xh+xw+biases)) @ W1 + b1 ----------
__global__ __launch_bounds__(512, 2) void k_ip(const float* __restrict__ x,
    const u16* __restrict__ WTh, const u16* __restrict__ WTw, const u16* __restrict__ WTc,
    const u16* __restrict__ WTattn, const u16* __restrict__ WT1,
    const float* __restrict__ bh, const float* __restrict__ bw, const float* __restrict__ bc,
    const float* __restrict__ b_attn, const float* __restrict__ b1,
    u16* __restrict__ x1_blk) {
  __shared__ alignas(16) u16 XS[65536];  // 128 KiB: X[pos][c], later XT[c][q], later OUT
  __shared__ alignas(16) u16 BB[16384];  // 32 KiB bounce: [64 rows][256 cols]
  WAVE_SETUP;
  const int t = blockIdx.x;
  const int d = t & 31, w1 = (t >> 5) & 1, h1 = (t >> 6) & 1, b = t >> 7;
  const int B0 = (((b * 32 + h1 * 16) * 32 + w1 * 16) * 32 + d) * 256;

  // ---- 1. stage XS[pos][c] ----
  for (int i = tid; i < 16384; i += 512) {
    int pos = i >> 6, c4 = (i & 63) << 2;
    const float4 v = *(const float4*)(x + B0 + (pos >> 4) * 262144 + (pos & 15) * 8192 + c4);
    u16x4 pk;
    pk[0] = f2b(v.x); pk[1] = f2b(v.y); pk[2] = f2b(v.z); pk[3] = f2b(v.w);
    *(u16x4*)((char*)XS + lds_off(pos, c4 * 2)) = pk;
  }
  __syncthreads();

  f32x4 sum[8][4];
  zero_acc<8, 4>(sum);

  // ---- 2. c-GEMM into sum: D[pos][c'] = sum_c X[pos][c] Wc[c][c'] ----
  gemmT<8, 4>(
      [&](int i, int kk) { return ld_lds(XS, wm * 128 + i * 16 + lr, kk * 64 + lk * 16); },
      [&](int j, int kk) { return ld_glb(WTc, wn * 64 + j * 16 + lr, kk * 64 + lk * 16); },
      sum);

  // biases bc + bh + bw (must precede att multiply)
#pragma unroll
  for (int i = 0; i < 8; ++i) {
    float bhv = bh[(wm * 8 + i) * 16 + lr];
#pragma unroll
    for (int r = 0; r < 4; ++r) {
      float bwv = bw[(lk * 4 + r) * 16 + lr];
#pragma unroll
      for (int j = 0; j < 4; ++j)
        sum[i][j][r] += bc[wn * 64 + j * 16 + lr] + bhv + bwv;
    }
  }

  // ---- 3. h-GEMM in 4 n-chunks; merge via BB ----
  // out[(lh',lw)][(lc,g')] = sum_{lh,g} X[(lh,lw)][(lc,g)] Wh[(lh,g)][(lh',g')]
#pragma unroll
  for (int q = 0; q < 4; ++q) {
    f32x4 hacc[8][1];
    zero_acc<8, 1>(hacc);
    gemmT<8, 1>(
        [&](int i, int kk) {
          int k = kk * 32 + lk * 8;
          return *(const bf16x8*)((const char*)XS +
                                  lds_off((k >> 4) * 16 + lr, (wm * 8 + i) * 32 + (k & 15) * 2));
        },
        [&](int j, int kk) { return ld_glb(WTh, q * 64 + wn * 16 + lr, kk * 64 + lk * 16); },
        hacc);
    __syncthreads();  // previous chunk read-adds done
#pragma unroll
    for (int i = 0; i < 8; ++i)
#pragma unroll
      for (int r = 0; r < 4; ++r)
        BB[lds_off(wn * 16 + lk * 4 + r, ((wm * 8 + i) * 16 + lr) * 2) >> 1] = f2b(hacc[i][0][r]);
    __syncthreads();
    if (wm == (q >> 1)) {
#pragma unroll
      for (int i2 = 0; i2 < 4; ++i2)
#pragma unroll
        for (int j = 0; j < 4; ++j)
#pragma unroll
          for (int r = 0; r < 4; ++r)
            sum[(q & 1) * 4 + i2][j][r] +=
                b2f(BB[lds_off(i2 * 16 + lk * 4 + r, (wn * 64 + j * 16 + lr) * 2) >> 1]);
    }
  }

  // ---- 4. w-GEMM in 4 n-chunks ----
  // out[(lh,lw')][(lc,g')] = sum_{lw,g} X[(lh,lw)][(lc,g)] Ww[(lw,g)][(lw',g')]
#pragma unroll
  for (int q = 0; q < 4; ++q) {
    f32x4 wacc[8][1];
    zero_acc<8, 1>(wacc);
    gemmT<8, 1>(
        [&](int i, int kk) {
          int k = kk * 32 + lk * 8;
          return *(const bf16x8*)((const char*)XS +
                                  lds_off(lr * 16 + (k >> 4), (wm * 8 + i) * 32 + (k & 15) * 2));
        },
        [&](int j, int kk) { return ld_glb(WTw, q * 64 + wn * 16 + lr, kk * 64 + lk * 16); },
        wacc);
    __syncthreads();
#pragma unroll
    for (int i = 0; i < 8; ++i)
#pragma unroll
      for (int r = 0; r < 4; ++r)
        BB[lds_off((lk * 4 + r) * 4 + wn, ((wm * 8 + i) * 16 + lr) * 2) >> 1] = f2b(wacc[i][0][r]);
    __syncthreads();
    if (lk == q) {
#pragma unroll
      for (int i = 0; i < 8; ++i)
#pragma unroll
        for (int j = 0; j < 4; ++j)
#pragma unroll
          for (int r = 0; r < 4; ++r)
            sum[i][j][r] +=
                b2f(BB[lds_off((wm * 8 + i) * 4 + r, (wn * 64 + j * 16 + lr) * 2) >> 1]);
    }
  }

  // ---- 5. restage XS as XT[c][q] (transposed) ----
  __syncthreads();  // safe: all XS GEMM reads retired at each chunk's first barrier
  for (int i = tid; i < 16384; i += 512) {
    int q = i >> 6, c4 = (i & 63) << 2;
    const float4 v = *(const float4*)(x + B0 + (q >> 4) * 262144 + (q & 15) * 8192 + c4);
    XS[lds_off(c4 + 0, q * 2) >> 1] = f2b(v.x);
    XS[lds_off(c4 + 1, q * 2) >> 1] = f2b(v.y);
    XS[lds_off(c4 + 2, q * 2) >> 1] = f2b(v.z);
    XS[lds_off(c4 + 3, q * 2) >> 1] = f2b(v.w);
  }
  __syncthreads();

  // ---- 6. att-GEMM in 4 n-chunks: D[c][p] = sum_q XT[c][q] WaT[p][q]; multiply ----
#pragma unroll
  for (int Q = 0; Q < 4; ++Q) {
    f32x4 aacc[8][1];
    zero_acc<8, 1>(aacc);
    gemmT<8, 1>(
        [&](int i, int kk) { return ld_lds(XS, wm * 128 + i * 16 + lr, kk * 64 + lk * 16); },
        [&](int j, int kk) { return ld_glb(WTattn, Q * 64 + wn * 16 + lr, kk * 64 + lk * 16); },
        aacc);
    float battn = b_attn[Q * 64 + wn * 16 + lr];
    __syncthreads();
#pragma unroll
    for (int i = 0; i < 8; ++i)
#pragma unroll
      for (int r = 0; r < 4; ++r)
        BB[lds_off(wn * 16 + lr, (wm * 128 + i * 16 + lk * 4 + r) * 2) >> 1] =
            f2b(aacc[i][0][r] + battn);
    __syncthreads();
    if (wm == (Q >> 1)) {
#pragma unroll
      for (int i2 = 0; i2 < 4; ++i2)
#pragma unroll
        for (int j = 0; j < 4; ++j)
#pragma unroll
          for (int r = 0; r < 4; ++r)
            sum[(Q & 1) * 4 + i2][j][r] *=
                1.0f + b2f(BB[lds_off(i2 * 16 + lk * 4 + r, (wn * 64 + j * 16 + lr) * 2) >> 1]);
    }
  }

  // ---- 7. bounce sum -> XS (OUT tile) ----
  __syncthreads();  // att GEMM reads of XT retired
#pragma unroll
  for (int i = 0; i < 8; ++i)
#pragma unroll
    for (int j = 0; j < 4; ++j)
#pragma unroll
      for (int r = 0; r < 4; ++r) {
        int pos = wm * 128 + i * 16 + lk * 4 + r;
        int c = wn * 64 + j * 16 + lr;
        XS[lds_off(pos, c * 2) >> 1] = f2b(sum[i][j][r]);
      }
  __syncthreads();

  // ---- 8. W1-GEMM ----
  zero_acc<8, 4>(sum);
  gemmT<8, 4>(
      [&](int i, int kk) { return ld_lds(XS, wm * 128 + i * 16 + lr, kk * 64 + lk * 16); },
      [&](int j, int kk) { return ld_glb(WT1, wn * 64 + j * 16 + lr, kk * 64 + lk * 16); },
      sum);
  __syncthreads();

  // ---- 9. bounce W1 out (+b1) -> XS; residual + wide store ----
#pragma unroll
  for (int i = 0; i < 8; ++i)
#pragma unroll
    for (int j = 0; j < 4; ++j)
#pragma unroll
      for (int r = 0; r < 4; ++r) {
        int pos = wm * 128 + i * 16 + lk * 4 + r;
        int c = wn * 64 + j * 16 + lr;
        XS[lds_off(pos, c * 2) >> 1] = f2b(sum[i][j][r] + b1[c]);
      }
  __syncthreads();
  u16* x1out = x1_blk + t * 65536;
  for (int i = tid; i < 8192; i += 512) {
    int pos = i >> 5, sB = (i & 31) << 4;
    bf16x8 v = *(const bf16x8*)((const char*)XS + pos * 512 + sB);
    int c8 = (sB ^ ((pos & 31) << 4)) >> 1;
    const float* gx = x + B0 + (pos >> 4) * 262144 + (pos & 15) * 8192 + c8;
    float4 f0 = *(const float4*)gx;
    float4 f1 = *(const float4*)(gx + 4);
    u16x8 o;
    o[0] = f2b(b2f((u16)v[0]) + f0.x); o[1] = f2b(b2f((u16)v[1]) + f0.y);
    o[2] = f2b(b2f((u16)v[2]) + f0.z); o[3] = f2b(b2f((u16)v[3]) + f0.w);
    o[4] = f2b(b2f((u16)v[4]) + f1.x); o[5] = f2b(b2f((u16)v[5]) + f1.y);
    o[6] = f2b(b2f((u16)v[6]) + f1.z); o[7] = f2b(b2f((u16)v[7]) + f1.w);
    *(u16x8*)(x1out + pos * 256 + c8) = o;
  }
}

// ---------- d-block gather GEMM (wlo-half blocks) ----------
__global__ __launch_bounds__(512, 4) void k_d(const u16* __restrict__ x1_blk,
    const u16* __restrict__ WTd, const float* __restrict__ bd, u16* __restrict__ xd) {
  __shared__ alignas(16) u16 XS[32768];  // [R 128][c 256]: R=(wloLoc,ld)
  WAVE_SETUP;
  const int bid = blockIdx.x;
  const int wh = bid & 1, d1 = (bid >> 1) & 1, wb = (bid >> 2) & 1,
            h = (bid >> 3) & 31, b = bid >> 8;
  const int tbase = b * 128 + (h >> 4) * 64 + wb * 32 + d1 * 16;
  const int posbase = (h & 15) * 16 + wh * 8;

  for (int i = tid; i < 4096; i += 512) {
    int Rl = i >> 5;              // wloLoc*16 + ld
    int c8 = (i & 31) << 3;
    int wloLoc = Rl >> 4, ld = Rl & 15;
    const u16x8 v = *(const u16x8*)(x1_blk + (size_t)(tbase + ld) * 65536 +
                                    (posbase + wloLoc) * 256 + c8);
    *(u16x8*)((char*)XS + lds_off(Rl, c8 * 2)) = v;
  }
  __syncthreads();

  f32x4 acc[4][4];
  zero_acc<4, 4>(acc);
  // m=(wloLoc,lc) k=(ld,g): A[m][k] = XS[(m>>4)*16+ld][lc*16+g]
  gemmT<4, 4>(
      [&](int i, int kk) {
        int k = kk * 32 + lk * 8;
        int khi = k >> 4, kloB = (k & 15) * 2;
        int mt = wm * 4 + i;
        return *(const bf16x8*)((const char*)XS + lds_off(mt * 16 + khi, lr * 32 + kloB));
      },
      [&](int j, int kk) { return ld_glb(WTd, wn * 64 + j * 16 + lr, kk * 64 + lk * 16); },
      acc);
  __syncthreads();
  // bounce: (mloc,n) -> row=(mloc>>4)*16+(n>>4), col=(mloc&15)*16+(n&15)
#pragma unroll
  for (int i = 0; i < 4; ++i)
#pragma unroll
    for (int j = 0; j < 4; ++j)
#pragma unroll
      for (int r = 0; r < 4; ++r) {
        int mloc = wm * 64 + i * 16 + lk * 4 + r;
        int n = wn * 64 + j * 16 + lr;
        int row = ((mloc >> 4) << 4) + (n >> 4);
        int col = ((mloc & 15) << 4) + (n & 15);
        XS[lds_off(row, col * 2) >> 1] = f2b(acc[i][j][r] + bd[n]);
      }
  __syncthreads();
  const int B0d = (((b * 32 + h) * 32 + wb * 16) * 32 + d1 * 16) * 256;
  for (int i = tid; i < 4096; i += 512) {
    int Rl = i >> 5, sB = (i & 31) << 4;
    bf16x8 v = *(const bf16x8*)((const char*)XS + Rl * 512 + sB);
    int c8 = (sB ^ ((Rl & 31) << 4)) >> 1;
    *(bf16x8*)(xd + B0d + (wh * 8 + (Rl >> 4)) * 8192 + (Rl & 15) * 256 + c8) = v;
  }
}

// ---------- fin: x2 = x1 + xd*W2 + b2; out = x2*(W3+I) + b3 (pos-half blocks) ----------
__global__ __launch_bounds__(512, 4) void k_fin(const u16* __restrict__ x1_blk,
    const u16* __restrict__ xd, const u16* __restrict__ WT2, const u16* __restrict__ WT3p,
    const float* __restrict__ b2, const float* __restrict__ b3, float* __restrict__ outp) {
  __shared__ alignas(16) u16 X2[32768];  // [128][256] bf16; later f32 bounce [64][256]
  WAVE_SETUP;
  const int ph = blockIdx.x & 1;
  const int vt = blockIdx.x >> 1;
  const int b = vt >> 7, h = (vt >> 2) & 31, w_hi = vt & 3;
  const size_t base = (size_t)vt * 65536;

  // stage x1 rows into X2 (wide); x1_blk is t-blocked
  for (int i = tid; i < 4096; i += 512) {
    int Rl = i >> 5, c8 = (i & 31) << 3;
    int rglob = ph * 128 + Rl;
    int w = w_hi * 8 + (rglob >> 5), d = rglob & 31;
    int t = b * 128 + (h >> 4) * 64 + (w >> 4) * 32 + d;
    int pos = (h & 15) * 16 + (w & 15);
    const u16x8 v = *(const u16x8*)(x1_blk + (size_t)t * 65536 + pos * 256 + c8);
    *(u16x8*)((char*)X2 + lds_off(Rl, c8 * 2)) = v;
  }

  // GEMM1: xd * W2 (A from global)
  const u16* xd_t = xd + base;
  f32x4 acc[4][4];
  zero_acc<4, 4>(acc);
  gemmT<4, 4>(
      [&](int i, int kk) { return ld_glb(xd_t, ph * 128 + wm * 64 + i * 16 + lr, kk * 64 + lk * 16); },
      [&](int j, int kk) { return ld_glb(WT2, wn * 64 + j * 16 + lr, kk * 64 + lk * 16); },
      acc);
  __syncthreads();

  // X2 = bf16(x1 + acc + b2)
#pragma unroll
  for (int i = 0; i < 4; ++i)
#pragma unroll
    for (int j = 0; j < 4; ++j)
#pragma unroll
      for (int r = 0; r < 4; ++r) {
        int mloc = wm * 64 + i * 16 + lk * 4 + r;
        int n = wn * 64 + j * 16 + lr;
        int off = lds_off(mloc, n * 2) >> 1;
        X2[off] = f2b(b2f(X2[off]) + acc[i][j][r] + b2[n]);
      }
  __syncthreads();

  // GEMM2: X2 * (W3+I)
  zero_acc<4, 4>(acc);
  gemmT<4, 4>(
      [&](int i, int kk) { return ld_lds(X2, wm * 64 + i * 16 + lr, kk * 64 + lk * 16); },
      [&](int j, int kk) { return ld_glb(WT3p, wn * 64 + j * 16 + lr, kk * 64 + lk * 16); },
      acc);

  // fp32 output via 2-round LDS bounce (64 rows each), float4 stores
  float* X2f = (float*)X2;
#pragma unroll
  for (int half = 0; half < 2; ++half) {
    __syncthreads();
    if (wm == half) {
#pragma unroll
      for (int i = 0; i < 4; ++i)
#pragma unroll
        for (int j = 0; j < 4; ++j)
#pragma unroll
          for (int r = 0; r < 4; ++r) {
            int row = i * 16 + lk * 4 + r;
            int n = wn * 64 + j * 16 + lr;
            X2f[row * 256 + n] = acc[i][j][r] + b3[n];
          }
    }
    __syncthreads();
    for (int i = tid; i < 4096; i += 512) {
      int row = i >> 6, c4 = (i & 63) << 2;
      f32x4 v = *(const f32x4*)(X2f + row * 256 + c4);
      *(f32x4*)(outp + base + (size_t)(ph * 128 + half * 64 + row) * 256 + c4) = v;
    }
  }
}

extern "C" void kernel_launch(void* const* d_in, const int* in_sizes, int n_in,
                              void* d_out, int out_size, void* d_ws, size_t ws_size,
                              hipStream_t stream) {
  (void)in_sizes; (void)n_in; (void)out_size; (void)ws_size;
  const float* x      = (const float*)d_in[0];
  const float* W_h    = (const float*)d_in[1];
  const float* b_h    = (const float*)d_in[2];
  const float* W_w    = (const float*)d_in[3];
  const float* b_w    = (const float*)d_in[4];
  const float* W_c    = (const float*)d_in[5];
  const float* b_c    = (const float*)d_in[6];
  const float* W_d    = (const float*)d_in[7];
  const float* b_d    = (const float*)d_in[8];
  const float* W_attn = (const float*)d_in[9];
  const float* b_attn = (const float*)d_in[10];
  const float* W_1    = (const float*)d_in[11];
  const float* b_1    = (const float*)d_in[12];
  const float* W_2    = (const float*)d_in[13];
  const float* b_2    = (const float*)d_in[14];
  const float* W_3    = (const float*)d_in[15];
  const float* b_3    = (const float*)d_in[16];
  float* outp = (float*)d_out;

  u16* WT = (u16*)d_ws;             // 8 * 65536 bf16 (1 MiB)
  u16* R1 = WT + 8 * 65536;         // 64 MiB: x1_blk (t-blocked bf16)
  u16* R2 = R1 + 33554432;          // 64 MiB: xd

  // slots: 0:h 1:w 2:c 3:attn 4:W1 5:Wd 6:W2 7:W3(+I)
  k_pack_all<<<2048, 64, 0, stream>>>(W_h, W_w, W_c, W_attn, W_1, W_d, W_2, W_3, WT);

  k_ip  <<<512, 512, 0, stream>>>(x, WT + 0 * 65536, WT + 1 * 65536, WT + 2 * 65536,
                                  WT + 3 * 65536, WT + 4 * 65536,
                                  b_h, b_w, b_c, b_attn, b_1, R1);
  k_d   <<<1024, 512, 0, stream>>>(R1, WT + 5 * 65536, b_d, R2);
  k_fin <<<1024, 512, 0, stream>>>(R1, R2, WT + 6 * 65536, WT + 7 * 65536, b_2, b_3, outp);
}